// Round 9
// baseline (1632.137 us; speedup 1.0000x reference)
//
#include <hip/hip_runtime.h>

#define DD 12
#define VOX 1728
#define BN_EPS 1e-5f
#define BATCH 512
#define PER 864
#define PERZ 865                                  // PER + 1 zero row per batch
#define NTOT (BATCH * PER)                        // 442368 points

typedef __attribute__((ext_vector_type(8))) short short8;   // 8 bf16 = 16B
typedef __attribute__((ext_vector_type(4))) float f32x4;
typedef unsigned short u16;

__device__ inline u16 f2b(float f) {              // fp32 -> bf16 RNE
    union { float f; unsigned u; } v; v.f = f;
    unsigned r = v.u + 0x7fffu + ((v.u >> 16) & 1u);
    return (u16)(r >> 16);
}
__device__ inline float b2f(u16 h) {
    union { unsigned u; float f; } v; v.u = ((unsigned)h) << 16;
    return v.f;
}
constexpr int ilog2(int v) { return v == 1 ? 0 : 1 + ilog2(v / 2); }

__device__ __forceinline__ void async_copy16(const void* g, void* l) {
    __builtin_amdgcn_global_load_lds(
        (const __attribute__((address_space(1))) void*)g,
        (__attribute__((address_space(3))) void*)l, 16, 0, 0);
}

// counted vmcnt wait; memory clobber pins memory-op motion across it
template<int N> __device__ __forceinline__ void wait_vm() {
    if constexpr (N == 0)       asm volatile("s_waitcnt vmcnt(0)"  ::: "memory");
    else if constexpr (N == 8)  asm volatile("s_waitcnt vmcnt(8)"  ::: "memory");
    else if constexpr (N == 10) asm volatile("s_waitcnt vmcnt(10)" ::: "memory");
    else if constexpr (N == 16) asm volatile("s_waitcnt vmcnt(16)" ::: "memory");
    else if constexpr (N == 18) asm volatile("s_waitcnt vmcnt(18)" ::: "memory");
    else static_assert(N == 0, "unhandled vmcnt value");
}

// ---------------- voxel -> point-row map ----------------
__global__ void build_map_kernel(const int* __restrict__ idx, int* __restrict__ map, int N) {
    int p = blockIdx.x * blockDim.x + threadIdx.x;
    if (p >= N) return;
    const int4 v = ((const int4*)idx)[p];
    map[v.x * VOX + (v.y * DD + v.z) * DD + v.w] = p;
}

// ---------------- neighbor table, TAP-MAJOR: nbr[tap][point] ----------------
__global__ void build_nbr_kernel(const int* __restrict__ idx, const int* __restrict__ map,
                                 u16* __restrict__ nbr, int N) {
    int p = blockIdx.x * blockDim.x + threadIdx.x;
    if (p >= N) return;
    const int4 v = ((const int4*)idx)[p];
    const int base = v.x * VOX;
    const int lb = v.x * PER;
    #pragma unroll
    for (int nk = 0; nk < 27; nk++) {
        int dz = nk / 9 - 1, dy = (nk / 3) % 3 - 1, dx = nk % 3 - 1;
        int zz = v.y + dz, yy = v.z + dy, xx = v.w + dx;
        u16 out = PER;
        if (zz >= 0 && zz < DD && yy >= 0 && yy < DD && xx >= 0 && xx < DD) {
            int q = map[base + (zz * DD + yy) * DD + xx];
            if (q >= 0) out = (u16)(q - lb);
        }
        nbr[nk * N + p] = out;
    }
    #pragma unroll
    for (int nk = 27; nk < 32; nk++) nbr[nk * N + p] = PER;
}

// ---------------- W [K][COUT] fp32 -> Wt [COUT][Kpad] bf16 (pad pre-zeroed) ----------------
__global__ void transpose_w_kernel(const float* __restrict__ W, u16* __restrict__ Wt,
                                   int K, int COUT, int Kpad) {
    int i = blockIdx.x * blockDim.x + threadIdx.x;
    if (i >= K * COUT) return;
    int n = i % COUT, k = i / COUT;
    Wt[(size_t)n * Kpad + k] = f2b(W[i]);
}

// ---------------- fp32 feats -> bf16, strided (PERZ) layout; zero rows inline ----------
__global__ void cast_bf16_kernel(const float* __restrict__ in, u16* __restrict__ out, int total4) {
    int i = blockIdx.x * blockDim.x + threadIdx.x;          // over BATCH*PERZ*4 (CIN=16)
    if (i >= total4) return;
    int p = i >> 2, c4 = i & 3;
    int b = p / PERZ, r = p - b * PERZ;
    ushort4 o = make_ushort4(0, 0, 0, 0);
    if (r < PER) {
        float4 v = ((const float4*)in)[(size_t)(b * PER + r) * 4 + c4];
        o.x = f2b(v.x); o.y = f2b(v.y); o.z = f2b(v.z); o.w = f2b(v.w);
    }
    ((ushort4*)out)[i] = o;
}

// ---------------- layer-1 conv (R8 structure, proven): BK=64, 4 waves, A+B LDS dbuf ----
template<int CIN, int COUT, int BM, int WM, int WN>
__global__ __launch_bounds__(256) void conv_mfma_kernel(
    const u16* __restrict__ fin, const u16* __restrict__ nbr, const u16* __restrict__ Wt,
    const float* __restrict__ bias, float* __restrict__ y, float* __restrict__ stats) {
    constexpr int Kpad   = (27 * CIN + 63) & ~63;
    constexpr int KSTEPS = Kpad / 64;
    constexpr int L2C    = ilog2(CIN);
    constexpr int BN     = WN * 64;
    constexpr int ASLOTS = BM / 32;
    constexpr int BSLOTS = BN / 32;
    constexpr int A_OFF  = BN * 128;
    constexpr int BUFB   = (BM + BN) * 128;
    static_assert(KSTEPS >= 3, "pipeline prologue needs >=3 K-steps");
    __shared__ char smem[2 * BUFB];

    const int perx = gridDim.x >> 3;
    const int bid = (blockIdx.x & 7) * perx + (blockIdx.x >> 3);
    const int p0 = bid * BM;

    const int tid = threadIdx.x;
    const int wave = tid >> 6, lane = tid & 63;
    const int wm = wave / WN, wn = wave % WN;
    const int lq = lane >> 4, lr = lane & 15;
    const int lrow = lane >> 3;
    const int kc_d = (lane & 7) ^ (lrow & 7);

    int qvoff[ASLOTS], gbase[ASLOTS];
    #pragma unroll
    for (int i = 0; i < ASLOTS; i++) {
        int m = (wave * ASLOTS + i) * 8 + lrow;
        int p = p0 + m;
        int b = p / PER;
        qvoff[i] = (((kc_d * 8) >> L2C) * NTOT + p) * 2;
        gbase[i] = b * PERZ * CIN + ((kc_d * 8) & (CIN - 1));
    }
    int bvoff[BSLOTS];
    #pragma unroll
    for (int j = 0; j < BSLOTS; j++)
        bvoff[j] = ((wave * BSLOTS + j) * 8 + lrow) * Kpad + kc_d * 8;

    int phs[2];
    phs[0] = ((0 + lq) ^ (lr & 7)) * 16;
    phs[1] = ((4 + lq) ^ (lr & 7)) * 16;
    const int aBase = A_OFF + (wm * 64 + lr) * 128;
    const int bBase = (wn * 64 + lr) * 128;

    const f32x4 fzero = {0.f, 0.f, 0.f, 0.f};
    f32x4 acc[4][4];
    #pragma unroll
    for (int i = 0; i < 4; i++)
        #pragma unroll
        for (int j = 0; j < 4; j++) acc[i][j] = fzero;

    u16 q[ASLOTS];
    auto loadQ = [&](int step) {
        int sQ = ((step * 64) >> L2C) * (NTOT * 2);
        #pragma unroll
        for (int i = 0; i < ASLOTS; i++)
            q[i] = *(const u16*)((const char*)nbr + qvoff[i] + sQ);
    };
    auto stage = [&](int step, int bo) {
        int sG = (step * 64) & (CIN - 1);
        const u16* fs = fin + sG;
        #pragma unroll
        for (int i = 0; i < ASLOTS; i++)
            async_copy16(fs + gbase[i] + ((int)q[i] << L2C),
                         smem + bo + A_OFF + (wave * ASLOTS + i) * 1024);
        const u16* wsrc = Wt + step * 64;
        #pragma unroll
        for (int j = 0; j < BSLOTS; j++)
            async_copy16(wsrc + bvoff[j], smem + bo + (wave * BSLOTS + j) * 1024);
    };

    loadQ(0);
    stage(0, 0);
    loadQ(1);

    #pragma unroll 1
    for (int kb = 0; kb < KSTEPS; kb++) {
        if (kb + 1 < KSTEPS) {
            stage(kb + 1, ((kb + 1) & 1) * BUFB);
            if (kb + 2 < KSTEPS) {
                loadQ(kb + 2);
                wait_vm<2 * ASLOTS + BSLOTS>();
            } else {
                wait_vm<ASLOTS + BSLOTS>();
            }
        } else {
            wait_vm<0>();
        }
        __builtin_amdgcn_s_barrier();

        const int so = (kb & 1) * BUFB;
        __builtin_amdgcn_s_setprio(1);
        #pragma unroll
        for (int s = 0; s < 2; s++) {
            short8 af[4], bfr[4];
            #pragma unroll
            for (int i = 0; i < 4; i++)
                af[i] = *(const short8*)(smem + so + aBase + i * 2048 + phs[s]);
            #pragma unroll
            for (int j = 0; j < 4; j++)
                bfr[j] = *(const short8*)(smem + so + bBase + j * 2048 + phs[s]);
            #pragma unroll
            for (int i = 0; i < 4; i++)
                #pragma unroll
                for (int j = 0; j < 4; j++)
                    acc[i][j] = __builtin_amdgcn_mfma_f32_16x16x32_bf16(af[i], bfr[j], acc[i][j], 0, 0, 0);
        }
        __builtin_amdgcn_s_setprio(0);
        asm volatile("s_waitcnt lgkmcnt(0)" ::: "memory");
        __builtin_amdgcn_s_barrier();
    }

    #pragma unroll
    for (int j = 0; j < 4; j++) {
        int col = wn * 64 + j * 16 + lr;
        float bv = bias[col];
        float s = 0.f, s2 = 0.f;
        #pragma unroll
        for (int i = 0; i < 4; i++) {
            int row0 = p0 + wm * 64 + i * 16 + lq * 4;
            #pragma unroll
            for (int r = 0; r < 4; r++) {
                float v = acc[i][j][r] + bv;
                y[(size_t)(row0 + r) * COUT + col] = v;
                s += v; s2 += v * v;
            }
        }
        s  += __shfl_down(s, 32);  s  += __shfl_down(s, 16);
        s2 += __shfl_down(s2, 32); s2 += __shfl_down(s2, 16);
        if (lane < 16) {
            atomicAdd(&stats[col], s);
            atomicAdd(&stats[COUT + col], s2);
        }
    }
}

// ---------------- layers 2/3: BK=128, 512 threads (8 waves of 32x64), 1 block/CU ------
// A double-buffered in LDS (2x64KB), B SINGLE-buffered (16KB): stageB(kb+1) issues after
// lgkmcnt(0)+barrier2 (all B(kb) reads retired block-wide) -> overwrite safe; landing is
// covered by the next step's counted wait. Half the K-steps of BK=64 => fixed per-step
// cost F amortized over 2x work. 16-chunk XOR swizzle keeps ds_read_b128 conflict-free.
// COUT=128 splits col-groups across grid (NG=2), pair adjacency preserved post-swizzle.
template<int CIN, int COUT, int NG>
__global__ __launch_bounds__(512) void conv512_kernel(
    const u16* __restrict__ fin,      // (BATCH*PERZ) x CIN bf16
    const u16* __restrict__ nbr,      // 32 x NTOT u16 (tap-major)
    const u16* __restrict__ Wt,       // COUT x Kpad bf16 (pad zeroed)
    const float* __restrict__ bias,
    float* __restrict__ y,
    float* __restrict__ stats) {
    constexpr int Kpad   = (27 * CIN + 127) & ~127;
    constexpr int KSTEPS = Kpad / 128;
    constexpr int TPT    = 128 / CIN;             // taps per K-step
    constexpr int BM     = 256, BN = 64;
    constexpr int ABUF   = BM * 256;              // 64KB per A buffer
    constexpr int BOFF   = 2 * ABUF;              // B single buffer after A dbuf
    static_assert(KSTEPS >= 3, "pipeline prologue needs >=3 K-steps");
    __shared__ char smem[2 * ABUF + BN * 256];    // 144KB

    const int perx = gridDim.x >> 3;
    const int bid = (blockIdx.x & 7) * perx + (blockIdx.x >> 3);
    const int colg = (NG > 1) ? (bid & (NG - 1)) : 0;
    const int rowb = (NG > 1) ? (bid >> 1) : bid;
    const int p0 = rowb * BM;

    const int tid = threadIdx.x;
    const int wave = tid >> 6, lane = tid & 63;
    const int lq = lane >> 4, lr = lane & 15;     // lq = DMA row-in-group, lr/cph roles
    const int cph = lane & 15;                    // physical 16B chunk (16 per 256B row)

    const char* nbrB = (const char*)nbr;
    const char* finB = (const char*)fin;
    const char* WtB  = (const char*)Wt;

    // ---- A staging invariants: 8 slots, 4 rows each (rows wave*32 .. wave*32+31) ----
    int qvoff[8], gbase[8];
    #pragma unroll
    for (int i = 0; i < 8; i++) {
        int rloc = i * 4 + lq;                    // row & 15 basis (wave*32 = 0 mod 16... mod 16 of i*4+lq)
        int cl   = cph ^ (rloc & 15);             // logical chunk this lane fetches
        int p    = p0 + wave * 32 + rloc;
        int b    = p / PER;
        int tstep = (cl * 8) / CIN;               // tap offset within step (0 or 0/1)
        qvoff[i] = (tstep * NTOT + p) * 2;        // bytes into tap-major nbr
        gbase[i] = (b * PERZ * CIN + ((cl * 8) & (CIN - 1))) * 2;   // bytes into fin
    }
    // ---- B staging invariants: 2 slots ----
    int bvoff[2];
    #pragma unroll
    for (int j = 0; j < 2; j++) {
        int rb = (wave * 2 + j) * 4 + lq;         // B row (output col local)
        int cl = cph ^ (rb & 15);
        int n  = colg * 64 + rb;
        bvoff[j] = (n * Kpad + cl * 8) * 2;       // + step*256 bytes
    }

    const f32x4 fzero = {0.f, 0.f, 0.f, 0.f};
    f32x4 acc[2][4];
    #pragma unroll
    for (int i = 0; i < 2; i++)
        #pragma unroll
        for (int j = 0; j < 4; j++) acc[i][j] = fzero;

    u16 q[8];
    auto loadQ = [&](int step) {
        int sQ = step * (TPT * NTOT * 2);
        #pragma unroll
        for (int i = 0; i < 8; i++)
            q[i] = *(const u16*)(nbrB + qvoff[i] + sQ);
    };
    auto stageA = [&](int bo) {
        #pragma unroll
        for (int i = 0; i < 8; i++)
            async_copy16(finB + gbase[i] + (int)q[i] * (CIN * 2),
                         smem + bo + (wave * 8 + i) * 1024 + lane * 16);
    };
    auto stageB = [&](int step) {
        const char* wsrc = WtB + step * 256;
        #pragma unroll
        for (int j = 0; j < 2; j++)
            async_copy16(wsrc + bvoff[j], smem + BOFF + (wave * 2 + j) * 1024 + lane * 16);
    };
    const int aRow = wave * 32 + lr;
    auto compute = [&](int bo) {
        #pragma unroll
        for (int s = 0; s < 4; s++) {
            const int cx = ((s * 4 + lq) ^ lr) * 16;
            short8 af[2], bfr[4];
            #pragma unroll
            for (int i = 0; i < 2; i++)
                af[i] = *(const short8*)(smem + bo + (aRow + i * 16) * 256 + cx);
            #pragma unroll
            for (int j = 0; j < 4; j++)
                bfr[j] = *(const short8*)(smem + BOFF + (j * 16 + lr) * 256 + cx);
            #pragma unroll
            for (int i = 0; i < 2; i++)
                #pragma unroll
                for (int j = 0; j < 4; j++)
                    acc[i][j] = __builtin_amdgcn_mfma_f32_16x16x32_bf16(af[i], bfr[j], acc[i][j], 0, 0, 0);
        }
    };

    // ---- prologue ----
    loadQ(0);
    stageA(0);                                    // buf0 <- A(0)   (auto-drains Q(0))
    stageB(0);                                    // Bbuf <- B(0)
    loadQ(1);

    #pragma unroll 1
    for (int kb = 0; kb < KSTEPS; kb++) {
        if (kb + 1 < KSTEPS) stageA(((kb + 1) & 1) * ABUF);   // q holds ids(kb+1)
        if (kb + 2 < KSTEPS) loadQ(kb + 2);
        if (kb + 1 < KSTEPS) {
            if (kb + 2 < KSTEPS) wait_vm<16>();   // drain B(kb) (A(kb),Q old drained by q-dep)
            else                 wait_vm<8>();
        } else {
            wait_vm<0>();
        }
        __builtin_amdgcn_s_barrier();             // A(kb)+B(kb) visible block-wide

        __builtin_amdgcn_s_setprio(1);
        compute((kb & 1) * ABUF);
        __builtin_amdgcn_s_setprio(0);
        asm volatile("s_waitcnt lgkmcnt(0)" ::: "memory");  // all ds_reads retired
        __builtin_amdgcn_s_barrier();             // block-wide: B buf + A buf^1 free
        if (kb + 1 < KSTEPS) stageB(kb + 1);      // safe overwrite of single B buffer
    }

    // ---- epilogue: bias, store y, fused per-channel sum/sumsq ----
    #pragma unroll
    for (int j = 0; j < 4; j++) {
        int col = colg * 64 + j * 16 + lr;
        float bv = bias[col];
        float s = 0.f, s2 = 0.f;
        #pragma unroll
        for (int i = 0; i < 2; i++) {
            int row0 = p0 + wave * 32 + i * 16 + lq * 4;
            #pragma unroll
            for (int r = 0; r < 4; r++) {
                float v = acc[i][j][r] + bv;
                y[(size_t)(row0 + r) * COUT + col] = v;
                s += v; s2 += v * v;
            }
        }
        s  += __shfl_down(s, 32);  s  += __shfl_down(s, 16);
        s2 += __shfl_down(s2, 32); s2 += __shfl_down(s2, 16);
        if (lane < 16) {
            atomicAdd(&stats[col], s);
            atomicAdd(&stats[COUT + col], s2);
        }
    }
}

// ---------------- fold BN into scale/shift ----------------
template<int COUT>
__global__ void finalize_kernel(const float* __restrict__ stats, const float* __restrict__ gamma,
                                const float* __restrict__ beta, float* __restrict__ ss, int N) {
    int co = threadIdx.x;
    float inv_n = 1.f / (float)N;
    float mu  = stats[co] * inv_n;
    float var = stats[COUT + co] * inv_n - mu * mu;
    float sc  = gamma[co] * rsqrtf(var + BN_EPS);
    ss[co]        = sc;
    ss[COUT + co] = beta[co] - mu * sc;
}

// ---------------- BN + ReLU, emit bf16 into strided (PERZ) layout; zero rows inline ----
template<int COUT>
__global__ void apply_kernel(const float* __restrict__ y, const float* __restrict__ ss,
                             u16* __restrict__ f, int total4) {
    int i = blockIdx.x * blockDim.x + threadIdx.x;          // over BATCH*PERZ*E4
    if (i >= total4) return;
    constexpr int E4 = COUT / 4;
    int p = i / E4, k = i - p * E4;
    int b = p / PERZ, r = p - b * PERZ;
    ushort4 o = make_ushort4(0, 0, 0, 0);
    if (r < PER) {
        float4 v = ((const float4*)y)[(size_t)(b * PER + r) * E4 + k];
        int c0 = k * 4;
        float a;
        a = fmaf(v.x, ss[c0 + 0], ss[COUT + c0 + 0]); o.x = f2b(a > 0.f ? a : 0.f);
        a = fmaf(v.y, ss[c0 + 1], ss[COUT + c0 + 1]); o.y = f2b(a > 0.f ? a : 0.f);
        a = fmaf(v.z, ss[c0 + 2], ss[COUT + c0 + 2]); o.z = f2b(a > 0.f ? a : 0.f);
        a = fmaf(v.w, ss[c0 + 3], ss[COUT + c0 + 3]); o.w = f2b(a > 0.f ? a : 0.f);
    }
    ((ushort4*)f)[i] = o;
}

// ---------------- legacy dense NCDHW output (from bf16 fbuf) ----------------
__global__ void output_kernel(const u16* __restrict__ f, const int* __restrict__ map,
                              float* __restrict__ out, int total) {
    int i = blockIdx.x * blockDim.x + threadIdx.x;
    if (i >= total) return;
    int voxel = i % VOX;
    int bc    = i / VOX;
    int c = bc & 63;
    int b = bc >> 6;
    int p = map[b * VOX + voxel];
    float v = 0.f;
    if (p >= 0) {
        int r = p - b * PER;
        v = b2f(f[(size_t)(b * PERZ + r) * 64 + c]);
    }
    out[i] = v;
}

// ---------------- fused BN+ReLU+scatter to dense NCDHW (LDS transpose, coalesced) ------
__global__ void output_fused_kernel(const float* __restrict__ y, const float* __restrict__ ss,
                                    const int* __restrict__ map, float* __restrict__ out) {
    __shared__ float tile[64][65];                // [voxel][c], +1 pad
    __shared__ int   prow[64];
    const int chunk = blockIdx.x;                 // BATCH * (VOX/64)
    const int b  = chunk / (VOX / 64);
    const int v0 = (chunk % (VOX / 64)) * 64;
    const int t = threadIdx.x;                    // 256
    if (t < 64) prow[t] = map[b * VOX + v0 + t];
    __syncthreads();
    const int c = t & 63;
    const float sc = ss[c], sh = ss[64 + c];
    for (int v = t >> 6; v < 64; v += 4) {
        int p = prow[v];
        float val = 0.f;
        if (p >= 0) {
            float a = fmaf(y[(size_t)p * 64 + c], sc, sh);
            val = a > 0.f ? a : 0.f;
        }
        tile[v][c] = val;
    }
    __syncthreads();
    const int vv = t & 63;
    #pragma unroll
    for (int cc = t >> 6; cc < 64; cc += 4)
        out[(size_t)(b * 64 + cc) * VOX + v0 + vv] = tile[vv][cc];
}

extern "C" void kernel_launch(void* const* d_in, const int* in_sizes, int n_in,
                              void* d_out, int out_size, void* d_ws, size_t ws_size,
                              hipStream_t stream) {
    const float* feats = (const float*)d_in[0];
    const int*   idx   = (const int*)  d_in[1];
    const float* W0 = (const float*)d_in[3];
    const float* b0 = (const float*)d_in[4];
    const float* g0 = (const float*)d_in[5];
    const float* e0 = (const float*)d_in[6];
    const float* W1 = (const float*)d_in[7];
    const float* b1 = (const float*)d_in[8];
    const float* g1 = (const float*)d_in[9];
    const float* e1 = (const float*)d_in[10];
    const float* W2 = (const float*)d_in[11];
    const float* b2 = (const float*)d_in[12];
    const float* g2 = (const float*)d_in[13];
    const float* e2 = (const float*)d_in[14];

    const int N = in_sizes[0] / 16;               // 442368

    // ---- workspace layout ----
    char* ws = (char*)d_ws;
    size_t off = 0;
    auto alloc = [&](size_t bytes) { void* p = ws + off; off = (off + bytes + 255) & ~(size_t)255; return p; };
    int*   map   = (int*)  alloc((size_t)BATCH * VOX * 4);
    float* stats = (float*)alloc(3 * 256 * 4);
    float* ss    = (float*)alloc(3 * 256 * 4);
    u16*   nbr   = (u16*)  alloc((size_t)N * 32 * 2);
    u16*   wt0   = (u16*)  alloc((size_t)64  * 448  * 2);
    u16*   wt1   = (u16*)  alloc((size_t)128 * 1792 * 2);           // Kpad=1792 (14x128)
    u16*   wt2   = (u16*)  alloc((size_t)64  * 3456 * 2);           // Kpad=3456 (27x128)
    u16*   fbuf  = (u16*)  alloc((size_t)BATCH * PERZ * 128 * 2);   // shared by all layers
    float* y = (float*)d_out;                     // fp32 conv out (layers 1/2), aliases d_out

    // layer-3 y gets its own buffer if workspace allows (enables fused output)
    const size_t y3_bytes = (size_t)N * 64 * 4;
    float* y3 = nullptr;
    if (off + y3_bytes <= ws_size) y3 = (float*)alloc(y3_bytes);

    hipMemsetAsync(map,   0xFF, (size_t)BATCH * VOX * 4, stream);
    hipMemsetAsync(stats, 0,    3 * 256 * 4, stream);
    hipMemsetAsync(wt0,   0,    (size_t)64  * 448  * 2, stream);    // zero K-pad
    hipMemsetAsync(wt1,   0,    (size_t)128 * 1792 * 2, stream);    // zero K-pad
    build_map_kernel<<<(N + 255) / 256, 256, 0, stream>>>(idx, map, N);
    build_nbr_kernel<<<(N + 255) / 256, 256, 0, stream>>>(idx, map, nbr, N);
    transpose_w_kernel<<<(432  * 64  + 255) / 256, 256, 0, stream>>>(W0, wt0, 432,  64,  448);
    transpose_w_kernel<<<(1728 * 128 + 255) / 256, 256, 0, stream>>>(W1, wt1, 1728, 128, 1792);
    transpose_w_kernel<<<(3456 * 64  + 255) / 256, 256, 0, stream>>>(W2, wt2, 3456, 64,  3456);

    // ---- layer 1: 16 -> 64 (BK=64, BM=256, 4 waves) ----
    cast_bf16_kernel<<<(BATCH * PERZ * 4 + 255) / 256, 256, 0, stream>>>(feats, fbuf, BATCH * PERZ * 4);
    conv_mfma_kernel<16, 64, 256, 4, 1><<<N / 256, 256, 0, stream>>>(fbuf, nbr, wt0, b0, y, stats + 0);
    finalize_kernel<64><<<1, 64, 0, stream>>>(stats + 0, g0, e0, ss + 0, N);
    apply_kernel<64><<<(BATCH * PERZ * 16 + 255) / 256, 256, 0, stream>>>(y, ss + 0, fbuf, BATCH * PERZ * 16);

    // ---- layer 2: 64 -> 128 (BK=128, BM=256, col-split x2, 512 threads) ----
    conv512_kernel<64, 128, 2><<<(N / 256) * 2, 512, 0, stream>>>(fbuf, nbr, wt1, b1, y, stats + 256);
    finalize_kernel<128><<<1, 128, 0, stream>>>(stats + 256, g1, e1, ss + 256, N);
    apply_kernel<128><<<(BATCH * PERZ * 32 + 255) / 256, 256, 0, stream>>>(y, ss + 256, fbuf, BATCH * PERZ * 32);

    // ---- layer 3: 128 -> 64 (BK=128, BM=256, 512 threads) ----
    float* yL3 = y3 ? y3 : y;
    conv512_kernel<128, 64, 1><<<N / 256, 512, 0, stream>>>(fbuf, nbr, wt2, b2, yL3, stats + 512);
    finalize_kernel<64><<<1, 64, 0, stream>>>(stats + 512, g2, e2, ss + 512, N);

    if (y3) {
        output_fused_kernel<<<BATCH * (VOX / 64), 256, 0, stream>>>(y3, ss + 512, map, (float*)d_out);
    } else {
        apply_kernel<64><<<(BATCH * PERZ * 16 + 255) / 256, 256, 0, stream>>>(y, ss + 512, fbuf, BATCH * PERZ * 16);
        output_kernel<<<(out_size + 255) / 256, 256, 0, stream>>>(fbuf, map, (float*)d_out, out_size);
    }
}

// Round 10
// 1230.367 us; speedup vs baseline: 1.3265x; 1.3265x over previous
//
#include <hip/hip_runtime.h>

#define DD 12
#define VOX 1728
#define BN_EPS 1e-5f
#define BATCH 512
#define PER 864
#define PERZ 865                                  // PER + 1 zero row per batch
#define NTOT (BATCH * PER)                        // 442368 points

typedef __attribute__((ext_vector_type(8))) short short8;   // 8 bf16 = 16B
typedef __attribute__((ext_vector_type(4))) float f32x4;
typedef unsigned short u16;

__device__ inline u16 f2b(float f) {              // fp32 -> bf16 RNE
    union { float f; unsigned u; } v; v.f = f;
    unsigned r = v.u + 0x7fffu + ((v.u >> 16) & 1u);
    return (u16)(r >> 16);
}
__device__ inline float b2f(u16 h) {
    union { unsigned u; float f; } v; v.u = ((unsigned)h) << 16;
    return v.f;
}
constexpr int ilog2(int v) { return v == 1 ? 0 : 1 + ilog2(v / 2); }

__device__ __forceinline__ void async_copy16(const void* g, void* l) {
    __builtin_amdgcn_global_load_lds(
        (const __attribute__((address_space(1))) void*)g,
        (__attribute__((address_space(3))) void*)l, 16, 0, 0);
}

// counted vmcnt wait; memory clobber pins memory-op motion across it
template<int N> __device__ __forceinline__ void wait_vm() {
    if constexpr (N == 0)       asm volatile("s_waitcnt vmcnt(0)"  ::: "memory");
    else if constexpr (N == 4)  asm volatile("s_waitcnt vmcnt(4)"  ::: "memory");
    else if constexpr (N == 8)  asm volatile("s_waitcnt vmcnt(8)"  ::: "memory");
    else if constexpr (N == 10) asm volatile("s_waitcnt vmcnt(10)" ::: "memory");
    else if constexpr (N == 12) asm volatile("s_waitcnt vmcnt(12)" ::: "memory");
    else if constexpr (N == 18) asm volatile("s_waitcnt vmcnt(18)" ::: "memory");
    else static_assert(N == 0, "unhandled vmcnt value");
}

// ---------------- voxel -> point-row map ----------------
__global__ void build_map_kernel(const int* __restrict__ idx, int* __restrict__ map, int N) {
    int p = blockIdx.x * blockDim.x + threadIdx.x;
    if (p >= N) return;
    const int4 v = ((const int4*)idx)[p];
    map[v.x * VOX + (v.y * DD + v.z) * DD + v.w] = p;
}

// ---------------- neighbor table, TAP-MAJOR: nbr[tap][point] ----------------
__global__ void build_nbr_kernel(const int* __restrict__ idx, const int* __restrict__ map,
                                 u16* __restrict__ nbr, int N) {
    int p = blockIdx.x * blockDim.x + threadIdx.x;
    if (p >= N) return;
    const int4 v = ((const int4*)idx)[p];
    const int base = v.x * VOX;
    const int lb = v.x * PER;
    #pragma unroll
    for (int nk = 0; nk < 27; nk++) {
        int dz = nk / 9 - 1, dy = (nk / 3) % 3 - 1, dx = nk % 3 - 1;
        int zz = v.y + dz, yy = v.z + dy, xx = v.w + dx;
        u16 out = PER;
        if (zz >= 0 && zz < DD && yy >= 0 && yy < DD && xx >= 0 && xx < DD) {
            int q = map[base + (zz * DD + yy) * DD + xx];
            if (q >= 0) out = (u16)(q - lb);
        }
        nbr[nk * N + p] = out;
    }
    #pragma unroll
    for (int nk = 27; nk < 32; nk++) nbr[nk * N + p] = PER;
}

// ---------------- W [K][COUT] fp32 -> Wt [COUT][Kpad] bf16 (pad pre-zeroed) ----------------
__global__ void transpose_w_kernel(const float* __restrict__ W, u16* __restrict__ Wt,
                                   int K, int COUT, int Kpad) {
    int i = blockIdx.x * blockDim.x + threadIdx.x;
    if (i >= K * COUT) return;
    int n = i % COUT, k = i / COUT;
    Wt[(size_t)n * Kpad + k] = f2b(W[i]);
}

// ---------------- fp32 feats -> bf16, strided (PERZ) layout; zero rows inline ----------
__global__ void cast_bf16_kernel(const float* __restrict__ in, u16* __restrict__ out, int total4) {
    int i = blockIdx.x * blockDim.x + threadIdx.x;          // over BATCH*PERZ*4 (CIN=16)
    if (i >= total4) return;
    int p = i >> 2, c4 = i & 3;
    int b = p / PERZ, r = p - b * PERZ;
    ushort4 o = make_ushort4(0, 0, 0, 0);
    if (r < PER) {
        float4 v = ((const float4*)in)[(size_t)(b * PER + r) * 4 + c4];
        o.x = f2b(v.x); o.y = f2b(v.y); o.z = f2b(v.z); o.w = f2b(v.w);
    }
    ((ushort4*)out)[i] = o;
}

// ---------------- conv (R8 proven): BK=64, A+B LDS double-buffer, counted vmcnt --------
template<int CIN, int COUT, int BM, int WM, int WN>
__global__ __launch_bounds__(256) void conv_mfma_kernel(
    const u16* __restrict__ fin, const u16* __restrict__ nbr, const u16* __restrict__ Wt,
    const float* __restrict__ bias, float* __restrict__ y, float* __restrict__ stats) {
    constexpr int Kpad   = (27 * CIN + 63) & ~63;
    constexpr int KSTEPS = Kpad / 64;
    constexpr int L2C    = ilog2(CIN);
    constexpr int BN     = WN * 64;
    constexpr int ASLOTS = BM / 32;
    constexpr int BSLOTS = BN / 32;
    constexpr int A_OFF  = BN * 128;
    constexpr int BUFB   = (BM + BN) * 128;
    static_assert(KSTEPS >= 3, "pipeline prologue needs >=3 K-steps");
    __shared__ char smem[2 * BUFB];

    const int perx = gridDim.x >> 3;
    const int bid = (blockIdx.x & 7) * perx + (blockIdx.x >> 3);
    const int p0 = bid * BM;

    const int tid = threadIdx.x;
    const int wave = tid >> 6, lane = tid & 63;
    const int wm = wave / WN, wn = wave % WN;
    const int lq = lane >> 4, lr = lane & 15;
    const int lrow = lane >> 3;
    const int kc_d = (lane & 7) ^ (lrow & 7);

    int qvoff[ASLOTS], gbase[ASLOTS];
    #pragma unroll
    for (int i = 0; i < ASLOTS; i++) {
        int m = (wave * ASLOTS + i) * 8 + lrow;
        int p = p0 + m;
        int b = p / PER;
        qvoff[i] = (((kc_d * 8) >> L2C) * NTOT + p) * 2;
        gbase[i] = b * PERZ * CIN + ((kc_d * 8) & (CIN - 1));
    }
    int bvoff[BSLOTS];
    #pragma unroll
    for (int j = 0; j < BSLOTS; j++)
        bvoff[j] = ((wave * BSLOTS + j) * 8 + lrow) * Kpad + kc_d * 8;

    int phs[2];
    phs[0] = ((0 + lq) ^ (lr & 7)) * 16;
    phs[1] = ((4 + lq) ^ (lr & 7)) * 16;
    const int aBase = A_OFF + (wm * 64 + lr) * 128;
    const int bBase = (wn * 64 + lr) * 128;

    const f32x4 fzero = {0.f, 0.f, 0.f, 0.f};
    f32x4 acc[4][4];
    #pragma unroll
    for (int i = 0; i < 4; i++)
        #pragma unroll
        for (int j = 0; j < 4; j++) acc[i][j] = fzero;

    u16 q[ASLOTS];
    auto loadQ = [&](int step) {
        int sQ = ((step * 64) >> L2C) * (NTOT * 2);
        #pragma unroll
        for (int i = 0; i < ASLOTS; i++)
            q[i] = *(const u16*)((const char*)nbr + qvoff[i] + sQ);
    };
    auto stage = [&](int step, int bo) {
        int sG = (step * 64) & (CIN - 1);
        const u16* fs = fin + sG;
        #pragma unroll
        for (int i = 0; i < ASLOTS; i++)
            async_copy16(fs + gbase[i] + ((int)q[i] << L2C),
                         smem + bo + A_OFF + (wave * ASLOTS + i) * 1024);
        const u16* wsrc = Wt + step * 64;
        #pragma unroll
        for (int j = 0; j < BSLOTS; j++)
            async_copy16(wsrc + bvoff[j], smem + bo + (wave * BSLOTS + j) * 1024);
    };

    loadQ(0);
    stage(0, 0);
    loadQ(1);

    #pragma unroll 1
    for (int kb = 0; kb < KSTEPS; kb++) {
        if (kb + 1 < KSTEPS) {
            stage(kb + 1, ((kb + 1) & 1) * BUFB);
            if (kb + 2 < KSTEPS) {
                loadQ(kb + 2);
                wait_vm<2 * ASLOTS + BSLOTS>();
            } else {
                wait_vm<ASLOTS + BSLOTS>();
            }
        } else {
            wait_vm<0>();
        }
        __builtin_amdgcn_s_barrier();

        const int so = (kb & 1) * BUFB;
        __builtin_amdgcn_s_setprio(1);
        #pragma unroll
        for (int s = 0; s < 2; s++) {
            short8 af[4], bfr[4];
            #pragma unroll
            for (int i = 0; i < 4; i++)
                af[i] = *(const short8*)(smem + so + aBase + i * 2048 + phs[s]);
            #pragma unroll
            for (int j = 0; j < 4; j++)
                bfr[j] = *(const short8*)(smem + so + bBase + j * 2048 + phs[s]);
            #pragma unroll
            for (int i = 0; i < 4; i++)
                #pragma unroll
                for (int j = 0; j < 4; j++)
                    acc[i][j] = __builtin_amdgcn_mfma_f32_16x16x32_bf16(af[i], bfr[j], acc[i][j], 0, 0, 0);
        }
        __builtin_amdgcn_s_setprio(0);
        asm volatile("s_waitcnt lgkmcnt(0)" ::: "memory");
        __builtin_amdgcn_s_barrier();
    }

    #pragma unroll
    for (int j = 0; j < 4; j++) {
        int col = wn * 64 + j * 16 + lr;
        float bv = bias[col];
        float s = 0.f, s2 = 0.f;
        #pragma unroll
        for (int i = 0; i < 4; i++) {
            int row0 = p0 + wm * 64 + i * 16 + lq * 4;
            #pragma unroll
            for (int r = 0; r < 4; r++) {
                float v = acc[i][j][r] + bv;
                y[(size_t)(row0 + r) * COUT + col] = v;
                s += v; s2 += v * v;
            }
        }
        s  += __shfl_down(s, 32);  s  += __shfl_down(s, 16);
        s2 += __shfl_down(s2, 32); s2 += __shfl_down(s2, 16);
        if (lane < 16) {
            atomicAdd(&stats[col], s);
            atomicAdd(&stats[COUT + col], s2);
        }
    }
}

// ---------------- layer-2 conv: same step structure, SINGLE-buffered B -> 48KB LDS ----
// B buffer (16KB) is overwritten by stageB(kb+1) at the step TAIL, after lgkmcnt(0)+
// barrier2 (all B(kb) reads retired block-wide; placement harness-verified in R9).
// Landing covered by next step's counted wait. 3 resident blocks/CU vs 2.
template<int CIN, int COUT, int BM, int WM, int WN>
__global__ __launch_bounds__(256) void conv_sB_kernel(
    const u16* __restrict__ fin, const u16* __restrict__ nbr, const u16* __restrict__ Wt,
    const float* __restrict__ bias, float* __restrict__ y, float* __restrict__ stats) {
    constexpr int Kpad   = (27 * CIN + 63) & ~63;
    constexpr int KSTEPS = Kpad / 64;
    constexpr int L2C    = ilog2(CIN);
    constexpr int BN     = WN * 64;
    constexpr int ASLOTS = BM / 32;
    constexpr int BSLOTS = BN / 32;
    constexpr int A_OFF  = BN * 128;              // B single buffer first, then A dbuf
    constexpr int ABUF   = BM * 128;
    static_assert(KSTEPS >= 3, "pipeline prologue needs >=3 K-steps");
    __shared__ char smem[A_OFF + 2 * ABUF];       // 16KB B + 2x16KB A = 48KB (BM=128)

    const int perx = gridDim.x >> 3;
    const int bid = (blockIdx.x & 7) * perx + (blockIdx.x >> 3);
    const int p0 = bid * BM;

    const int tid = threadIdx.x;
    const int wave = tid >> 6, lane = tid & 63;
    const int wm = wave / WN, wn = wave % WN;
    const int lq = lane >> 4, lr = lane & 15;
    const int lrow = lane >> 3;
    const int kc_d = (lane & 7) ^ (lrow & 7);

    int qvoff[ASLOTS], gbase[ASLOTS];
    #pragma unroll
    for (int i = 0; i < ASLOTS; i++) {
        int m = (wave * ASLOTS + i) * 8 + lrow;
        int p = p0 + m;
        int b = p / PER;
        qvoff[i] = (((kc_d * 8) >> L2C) * NTOT + p) * 2;
        gbase[i] = b * PERZ * CIN + ((kc_d * 8) & (CIN - 1));
    }
    int bvoff[BSLOTS];
    #pragma unroll
    for (int j = 0; j < BSLOTS; j++)
        bvoff[j] = ((wave * BSLOTS + j) * 8 + lrow) * Kpad + kc_d * 8;

    int phs[2];
    phs[0] = ((0 + lq) ^ (lr & 7)) * 16;
    phs[1] = ((4 + lq) ^ (lr & 7)) * 16;
    const int aBase = A_OFF + (wm * 64 + lr) * 128;
    const int bBase = (wn * 64 + lr) * 128;

    const f32x4 fzero = {0.f, 0.f, 0.f, 0.f};
    f32x4 acc[4][4];
    #pragma unroll
    for (int i = 0; i < 4; i++)
        #pragma unroll
        for (int j = 0; j < 4; j++) acc[i][j] = fzero;

    u16 q[ASLOTS];
    auto loadQ = [&](int step) {
        int sQ = ((step * 64) >> L2C) * (NTOT * 2);
        #pragma unroll
        for (int i = 0; i < ASLOTS; i++)
            q[i] = *(const u16*)((const char*)nbr + qvoff[i] + sQ);
    };
    auto stageA = [&](int step, int bo) {
        int sG = (step * 64) & (CIN - 1);
        const u16* fs = fin + sG;
        #pragma unroll
        for (int i = 0; i < ASLOTS; i++)
            async_copy16(fs + gbase[i] + ((int)q[i] << L2C),
                         smem + bo + (wave * ASLOTS + i) * 1024);
    };
    auto stageB = [&](int step) {
        const u16* wsrc = Wt + step * 64;
        #pragma unroll
        for (int j = 0; j < BSLOTS; j++)
            async_copy16(wsrc + bvoff[j], smem + (wave * BSLOTS + j) * 1024);
    };

    // prologue
    loadQ(0);
    stageA(0, A_OFF);
    stageB(0);
    loadQ(1);

    #pragma unroll 1
    for (int kb = 0; kb < KSTEPS; kb++) {
        // top: prefetch A(kb+1) into other A buffer; q already holds ids(kb+1)
        if (kb + 1 < KSTEPS) {
            stageA(kb + 1, A_OFF + ((kb + 1) & 1) * ABUF);
            if (kb + 2 < KSTEPS) {
                loadQ(kb + 2);
                wait_vm<2 * ASLOTS>();            // leave stageA(kb+1)+loadQ(kb+2);
            } else {                              // drains stageB(kb) & older
                wait_vm<ASLOTS>();
            }
        } else {
            wait_vm<0>();
        }
        __builtin_amdgcn_s_barrier();             // A(kb)+B(kb) visible block-wide

        const int so = A_OFF + (kb & 1) * ABUF;
        __builtin_amdgcn_s_setprio(1);
        #pragma unroll
        for (int s = 0; s < 2; s++) {
            short8 af[4], bfr[4];
            #pragma unroll
            for (int i = 0; i < 4; i++)
                af[i] = *(const short8*)(smem + so + aBase - A_OFF + i * 2048 + phs[s]);
            #pragma unroll
            for (int j = 0; j < 4; j++)
                bfr[j] = *(const short8*)(smem + bBase + j * 2048 + phs[s]);
            #pragma unroll
            for (int i = 0; i < 4; i++)
                #pragma unroll
                for (int j = 0; j < 4; j++)
                    acc[i][j] = __builtin_amdgcn_mfma_f32_16x16x32_bf16(af[i], bfr[j], acc[i][j], 0, 0, 0);
        }
        __builtin_amdgcn_s_setprio(0);
        asm volatile("s_waitcnt lgkmcnt(0)" ::: "memory");  // all ds_reads retired
        __builtin_amdgcn_s_barrier();             // B buf + other A buf free block-wide
        if (kb + 1 < KSTEPS) stageB(kb + 1);      // tail: overwrite single B buffer
    }

    #pragma unroll
    for (int j = 0; j < 4; j++) {
        int col = wn * 64 + j * 16 + lr;
        float bv = bias[col];
        float s = 0.f, s2 = 0.f;
        #pragma unroll
        for (int i = 0; i < 4; i++) {
            int row0 = p0 + wm * 64 + i * 16 + lq * 4;
            #pragma unroll
            for (int r = 0; r < 4; r++) {
                float v = acc[i][j][r] + bv;
                y[(size_t)(row0 + r) * COUT + col] = v;
                s += v; s2 += v * v;
            }
        }
        s  += __shfl_down(s, 32);  s  += __shfl_down(s, 16);
        s2 += __shfl_down(s2, 32); s2 += __shfl_down(s2, 16);
        if (lane < 16) {
            atomicAdd(&stats[col], s);
            atomicAdd(&stats[COUT + col], s2);
        }
    }
}

// ---------------- fold BN into scale/shift ----------------
template<int COUT>
__global__ void finalize_kernel(const float* __restrict__ stats, const float* __restrict__ gamma,
                                const float* __restrict__ beta, float* __restrict__ ss, int N) {
    int co = threadIdx.x;
    float inv_n = 1.f / (float)N;
    float mu  = stats[co] * inv_n;
    float var = stats[COUT + co] * inv_n - mu * mu;
    float sc  = gamma[co] * rsqrtf(var + BN_EPS);
    ss[co]        = sc;
    ss[COUT + co] = beta[co] - mu * sc;
}

// ---------------- BN + ReLU, emit bf16 into strided (PERZ) layout; zero rows inline ----
template<int COUT>
__global__ void apply_kernel(const float* __restrict__ y, const float* __restrict__ ss,
                             u16* __restrict__ f, int total4) {
    int i = blockIdx.x * blockDim.x + threadIdx.x;          // over BATCH*PERZ*E4
    if (i >= total4) return;
    constexpr int E4 = COUT / 4;
    int p = i / E4, k = i - p * E4;
    int b = p / PERZ, r = p - b * PERZ;
    ushort4 o = make_ushort4(0, 0, 0, 0);
    if (r < PER) {
        float4 v = ((const float4*)y)[(size_t)(b * PER + r) * E4 + k];
        int c0 = k * 4;
        float a;
        a = fmaf(v.x, ss[c0 + 0], ss[COUT + c0 + 0]); o.x = f2b(a > 0.f ? a : 0.f);
        a = fmaf(v.y, ss[c0 + 1], ss[COUT + c0 + 1]); o.y = f2b(a > 0.f ? a : 0.f);
        a = fmaf(v.z, ss[c0 + 2], ss[COUT + c0 + 2]); o.z = f2b(a > 0.f ? a : 0.f);
        a = fmaf(v.w, ss[c0 + 3], ss[COUT + c0 + 3]); o.w = f2b(a > 0.f ? a : 0.f);
    }
    ((ushort4*)f)[i] = o;
}

// ---------------- legacy dense NCDHW output (from bf16 fbuf) ----------------
__global__ void output_kernel(const u16* __restrict__ f, const int* __restrict__ map,
                              float* __restrict__ out, int total) {
    int i = blockIdx.x * blockDim.x + threadIdx.x;
    if (i >= total) return;
    int voxel = i % VOX;
    int bc    = i / VOX;
    int c = bc & 63;
    int b = bc >> 6;
    int p = map[b * VOX + voxel];
    float v = 0.f;
    if (p >= 0) {
        int r = p - b * PER;
        v = b2f(f[(size_t)(b * PERZ + r) * 64 + c]);
    }
    out[i] = v;
}

// ---------------- fused BN+ReLU+scatter to dense NCDHW (LDS transpose, coalesced) ------
__global__ void output_fused_kernel(const float* __restrict__ y, const float* __restrict__ ss,
                                    const int* __restrict__ map, float* __restrict__ out) {
    __shared__ float tile[64][65];                // [voxel][c], +1 pad
    __shared__ int   prow[64];
    const int chunk = blockIdx.x;                 // BATCH * (VOX/64)
    const int b  = chunk / (VOX / 64);
    const int v0 = (chunk % (VOX / 64)) * 64;
    const int t = threadIdx.x;                    // 256
    if (t < 64) prow[t] = map[b * VOX + v0 + t];
    __syncthreads();
    const int c = t & 63;
    const float sc = ss[c], sh = ss[64 + c];
    for (int v = t >> 6; v < 64; v += 4) {
        int p = prow[v];
        float val = 0.f;
        if (p >= 0) {
            float a = fmaf(y[(size_t)p * 64 + c], sc, sh);
            val = a > 0.f ? a : 0.f;
        }
        tile[v][c] = val;
    }
    __syncthreads();
    const int vv = t & 63;
    #pragma unroll
    for (int cc = t >> 6; cc < 64; cc += 4)
        out[(size_t)(b * 64 + cc) * VOX + v0 + vv] = tile[vv][cc];
}

extern "C" void kernel_launch(void* const* d_in, const int* in_sizes, int n_in,
                              void* d_out, int out_size, void* d_ws, size_t ws_size,
                              hipStream_t stream) {
    const float* feats = (const float*)d_in[0];
    const int*   idx   = (const int*)  d_in[1];
    const float* W0 = (const float*)d_in[3];
    const float* b0 = (const float*)d_in[4];
    const float* g0 = (const float*)d_in[5];
    const float* e0 = (const float*)d_in[6];
    const float* W1 = (const float*)d_in[7];
    const float* b1 = (const float*)d_in[8];
    const float* g1 = (const float*)d_in[9];
    const float* e1 = (const float*)d_in[10];
    const float* W2 = (const float*)d_in[11];
    const float* b2 = (const float*)d_in[12];
    const float* g2 = (const float*)d_in[13];
    const float* e2 = (const float*)d_in[14];

    const int N = in_sizes[0] / 16;               // 442368

    // ---- workspace layout ----
    char* ws = (char*)d_ws;
    size_t off = 0;
    auto alloc = [&](size_t bytes) { void* p = ws + off; off = (off + bytes + 255) & ~(size_t)255; return p; };
    int*   map   = (int*)  alloc((size_t)BATCH * VOX * 4);
    float* stats = (float*)alloc(3 * 256 * 4);
    float* ss    = (float*)alloc(3 * 256 * 4);
    u16*   nbr   = (u16*)  alloc((size_t)N * 32 * 2);
    u16*   wt0   = (u16*)  alloc((size_t)64  * 448  * 2);
    u16*   wt1   = (u16*)  alloc((size_t)128 * 1728 * 2);
    u16*   wt2   = (u16*)  alloc((size_t)64  * 3456 * 2);
    u16*   fbuf  = (u16*)  alloc((size_t)BATCH * PERZ * 128 * 2);   // shared by all layers
    float* y = (float*)d_out;                     // fp32 conv out (layers 1/2), aliases d_out

    // layer-3 y gets its own buffer if workspace allows (enables fused output)
    const size_t y3_bytes = (size_t)N * 64 * 4;
    float* y3 = nullptr;
    if (off + y3_bytes <= ws_size) y3 = (float*)alloc(y3_bytes);

    hipMemsetAsync(map,   0xFF, (size_t)BATCH * VOX * 4, stream);
    hipMemsetAsync(stats, 0,    3 * 256 * 4, stream);
    hipMemsetAsync(wt0,   0,    (size_t)64 * 448 * 2, stream);      // zero K-pad
    build_map_kernel<<<(N + 255) / 256, 256, 0, stream>>>(idx, map, N);
    build_nbr_kernel<<<(N + 255) / 256, 256, 0, stream>>>(idx, map, nbr, N);
    transpose_w_kernel<<<(432  * 64  + 255) / 256, 256, 0, stream>>>(W0, wt0, 432,  64,  448);
    transpose_w_kernel<<<(1728 * 128 + 255) / 256, 256, 0, stream>>>(W1, wt1, 1728, 128, 1728);
    transpose_w_kernel<<<(3456 * 64  + 255) / 256, 256, 0, stream>>>(W2, wt2, 3456, 64,  3456);

    // ---- layer 1: 16 -> 64 (BM=256, waves 4x1) ----
    cast_bf16_kernel<<<(BATCH * PERZ * 4 + 255) / 256, 256, 0, stream>>>(feats, fbuf, BATCH * PERZ * 4);
    conv_mfma_kernel<16, 64, 256, 4, 1><<<N / 256, 256, 0, stream>>>(fbuf, nbr, wt0, b0, y, stats + 0);
    finalize_kernel<64><<<1, 64, 0, stream>>>(stats + 0, g0, e0, ss + 0, N);
    apply_kernel<64><<<(BATCH * PERZ * 16 + 255) / 256, 256, 0, stream>>>(y, ss + 0, fbuf, BATCH * PERZ * 16);

    // ---- layer 2: 64 -> 128 (BM=128, waves 2x2, single-B 48KB -> 3 blocks/CU) ----
    conv_sB_kernel<64, 128, 128, 2, 2><<<N / 128, 256, 0, stream>>>(fbuf, nbr, wt1, b1, y, stats + 256);
    finalize_kernel<128><<<1, 128, 0, stream>>>(stats + 256, g1, e1, ss + 256, N);
    apply_kernel<128><<<(BATCH * PERZ * 32 + 255) / 256, 256, 0, stream>>>(y, ss + 256, fbuf, BATCH * PERZ * 32);

    // ---- layer 3: 128 -> 64 (BM=256, waves 4x1) ----
    float* yL3 = y3 ? y3 : y;
    conv_mfma_kernel<128, 64, 256, 4, 1><<<N / 256, 256, 0, stream>>>(fbuf, nbr, wt2, b2, yL3, stats + 512);
    finalize_kernel<64><<<1, 64, 0, stream>>>(stats + 512, g2, e2, ss + 512, N);

    if (y3) {
        output_fused_kernel<<<BATCH * (VOX / 64), 256, 0, stream>>>(y3, ss + 512, map, (float*)d_out);
    } else {
        apply_kernel<64><<<(BATCH * PERZ * 16 + 255) / 256, 256, 0, stream>>>(y, ss + 512, fbuf, BATCH * PERZ * 16);
        output_kernel<<<(out_size + 255) / 256, 256, 0, stream>>>(fbuf, map, (float*)d_out, out_size);
    }
}

// Round 11
// 1201.657 us; speedup vs baseline: 1.3582x; 1.0239x over previous
//
#include <hip/hip_runtime.h>

#define DD 12
#define VOX 1728
#define BN_EPS 1e-5f
#define BATCH 512
#define PER 864
#define PERZ 865                                  // PER + 1 zero row per batch
#define NTOT (BATCH * PER)                        // 442368 points

typedef __attribute__((ext_vector_type(8))) short short8;   // 8 bf16 = 16B
typedef __attribute__((ext_vector_type(4))) float f32x4;
typedef unsigned short u16;

__device__ inline u16 f2b(float f) {              // fp32 -> bf16 RNE
    union { float f; unsigned u; } v; v.f = f;
    unsigned r = v.u + 0x7fffu + ((v.u >> 16) & 1u);
    return (u16)(r >> 16);
}
__device__ inline float b2f(u16 h) {
    union { unsigned u; float f; } v; v.u = ((unsigned)h) << 16;
    return v.f;
}
constexpr int ilog2(int v) { return v == 1 ? 0 : 1 + ilog2(v / 2); }

__device__ __forceinline__ void async_copy16(const void* g, void* l) {
    __builtin_amdgcn_global_load_lds(
        (const __attribute__((address_space(1))) void*)g,
        (__attribute__((address_space(3))) void*)l, 16, 0, 0);
}

// counted vmcnt wait; memory clobber pins memory-op motion across it
template<int N> __device__ __forceinline__ void wait_vm() {
    if constexpr (N == 0)       asm volatile("s_waitcnt vmcnt(0)"  ::: "memory");
    else if constexpr (N == 8)  asm volatile("s_waitcnt vmcnt(8)"  ::: "memory");
    else if constexpr (N == 10) asm volatile("s_waitcnt vmcnt(10)" ::: "memory");
    else if constexpr (N == 12) asm volatile("s_waitcnt vmcnt(12)" ::: "memory");
    else if constexpr (N == 18) asm volatile("s_waitcnt vmcnt(18)" ::: "memory");
    else static_assert(N == 0, "unhandled vmcnt value");
}

// ---------------- voxel -> point-row map ----------------
__global__ void build_map_kernel(const int* __restrict__ idx, int* __restrict__ map, int N) {
    int p = blockIdx.x * blockDim.x + threadIdx.x;
    if (p >= N) return;
    const int4 v = ((const int4*)idx)[p];
    map[v.x * VOX + (v.y * DD + v.z) * DD + v.w] = p;
}

// ---------------- neighbor table, TAP-MAJOR: nbr[tap][point] ----------------
__global__ void build_nbr_kernel(const int* __restrict__ idx, const int* __restrict__ map,
                                 u16* __restrict__ nbr, int N) {
    int p = blockIdx.x * blockDim.x + threadIdx.x;
    if (p >= N) return;
    const int4 v = ((const int4*)idx)[p];
    const int base = v.x * VOX;
    const int lb = v.x * PER;
    #pragma unroll
    for (int nk = 0; nk < 27; nk++) {
        int dz = nk / 9 - 1, dy = (nk / 3) % 3 - 1, dx = nk % 3 - 1;
        int zz = v.y + dz, yy = v.z + dy, xx = v.w + dx;
        u16 out = PER;
        if (zz >= 0 && zz < DD && yy >= 0 && yy < DD && xx >= 0 && xx < DD) {
            int q = map[base + (zz * DD + yy) * DD + xx];
            if (q >= 0) out = (u16)(q - lb);
        }
        nbr[nk * N + p] = out;
    }
    #pragma unroll
    for (int nk = 27; nk < 32; nk++) nbr[nk * N + p] = PER;
}

// ---------------- W [K][COUT] fp32 -> Wt [COUT][Kpad] bf16 (pad pre-zeroed) ----------------
__global__ void transpose_w_kernel(const float* __restrict__ W, u16* __restrict__ Wt,
                                   int K, int COUT, int Kpad) {
    int i = blockIdx.x * blockDim.x + threadIdx.x;
    if (i >= K * COUT) return;
    int n = i % COUT, k = i / COUT;
    Wt[(size_t)n * Kpad + k] = f2b(W[i]);
}

// ---------------- fp32 feats -> bf16, strided (PERZ) layout; zero rows inline ----------
__global__ void cast_bf16_kernel(const float* __restrict__ in, u16* __restrict__ out, int total4) {
    int i = blockIdx.x * blockDim.x + threadIdx.x;          // over BATCH*PERZ*4 (CIN=16)
    if (i >= total4) return;
    int p = i >> 2, c4 = i & 3;
    int b = p / PERZ, r = p - b * PERZ;
    ushort4 o = make_ushort4(0, 0, 0, 0);
    if (r < PER) {
        float4 v = ((const float4*)in)[(size_t)(b * PER + r) * 4 + c4];
        o.x = f2b(v.x); o.y = f2b(v.y); o.z = f2b(v.z); o.w = f2b(v.w);
    }
    ((ushort4*)out)[i] = o;
}

// ---------------- conv (R8 proven optimum): BK=64, A+B LDS dbuf, counted vmcnt, setprio -
template<int CIN, int COUT, int BM, int WM, int WN>
__global__ __launch_bounds__(256) void conv_mfma_kernel(
    const u16* __restrict__ fin, const u16* __restrict__ nbr, const u16* __restrict__ Wt,
    const float* __restrict__ bias, float* __restrict__ y, float* __restrict__ stats) {
    constexpr int Kpad   = (27 * CIN + 63) & ~63;
    constexpr int KSTEPS = Kpad / 64;
    constexpr int L2C    = ilog2(CIN);
    constexpr int BN     = WN * 64;
    constexpr int ASLOTS = BM / 32;
    constexpr int BSLOTS = BN / 32;
    constexpr int A_OFF  = BN * 128;
    constexpr int BUFB   = (BM + BN) * 128;
    static_assert(KSTEPS >= 3, "pipeline prologue needs >=3 K-steps");
    __shared__ char smem[2 * BUFB];

    const int perx = gridDim.x >> 3;
    const int bid = (blockIdx.x & 7) * perx + (blockIdx.x >> 3);
    const int p0 = bid * BM;

    const int tid = threadIdx.x;
    const int wave = tid >> 6, lane = tid & 63;
    const int wm = wave / WN, wn = wave % WN;
    const int lq = lane >> 4, lr = lane & 15;
    const int lrow = lane >> 3;
    const int kc_d = (lane & 7) ^ (lrow & 7);

    int qvoff[ASLOTS], gbase[ASLOTS];
    #pragma unroll
    for (int i = 0; i < ASLOTS; i++) {
        int m = (wave * ASLOTS + i) * 8 + lrow;
        int p = p0 + m;
        int b = p / PER;
        qvoff[i] = (((kc_d * 8) >> L2C) * NTOT + p) * 2;
        gbase[i] = b * PERZ * CIN + ((kc_d * 8) & (CIN - 1));
    }
    int bvoff[BSLOTS];
    #pragma unroll
    for (int j = 0; j < BSLOTS; j++)
        bvoff[j] = ((wave * BSLOTS + j) * 8 + lrow) * Kpad + kc_d * 8;

    int phs[2];
    phs[0] = ((0 + lq) ^ (lr & 7)) * 16;
    phs[1] = ((4 + lq) ^ (lr & 7)) * 16;
    const int aBase = A_OFF + (wm * 64 + lr) * 128;
    const int bBase = (wn * 64 + lr) * 128;

    const f32x4 fzero = {0.f, 0.f, 0.f, 0.f};
    f32x4 acc[4][4];
    #pragma unroll
    for (int i = 0; i < 4; i++)
        #pragma unroll
        for (int j = 0; j < 4; j++) acc[i][j] = fzero;

    u16 q[ASLOTS];
    auto loadQ = [&](int step) {
        int sQ = ((step * 64) >> L2C) * (NTOT * 2);
        #pragma unroll
        for (int i = 0; i < ASLOTS; i++)
            q[i] = *(const u16*)((const char*)nbr + qvoff[i] + sQ);
    };
    auto stage = [&](int step, int bo) {
        int sG = (step * 64) & (CIN - 1);
        const u16* fs = fin + sG;
        #pragma unroll
        for (int i = 0; i < ASLOTS; i++)
            async_copy16(fs + gbase[i] + ((int)q[i] << L2C),
                         smem + bo + A_OFF + (wave * ASLOTS + i) * 1024);
        const u16* wsrc = Wt + step * 64;
        #pragma unroll
        for (int j = 0; j < BSLOTS; j++)
            async_copy16(wsrc + bvoff[j], smem + bo + (wave * BSLOTS + j) * 1024);
    };

    loadQ(0);
    stage(0, 0);
    loadQ(1);

    #pragma unroll 1
    for (int kb = 0; kb < KSTEPS; kb++) {
        if (kb + 1 < KSTEPS) {
            stage(kb + 1, ((kb + 1) & 1) * BUFB);
            if (kb + 2 < KSTEPS) {
                loadQ(kb + 2);
                wait_vm<2 * ASLOTS + BSLOTS>();
            } else {
                wait_vm<ASLOTS + BSLOTS>();
            }
        } else {
            wait_vm<0>();
        }
        __builtin_amdgcn_s_barrier();

        const int so = (kb & 1) * BUFB;
        __builtin_amdgcn_s_setprio(1);
        #pragma unroll
        for (int s = 0; s < 2; s++) {
            short8 af[4], bfr[4];
            #pragma unroll
            for (int i = 0; i < 4; i++)
                af[i] = *(const short8*)(smem + so + aBase + i * 2048 + phs[s]);
            #pragma unroll
            for (int j = 0; j < 4; j++)
                bfr[j] = *(const short8*)(smem + so + bBase + j * 2048 + phs[s]);
            #pragma unroll
            for (int i = 0; i < 4; i++)
                #pragma unroll
                for (int j = 0; j < 4; j++)
                    acc[i][j] = __builtin_amdgcn_mfma_f32_16x16x32_bf16(af[i], bfr[j], acc[i][j], 0, 0, 0);
        }
        __builtin_amdgcn_s_setprio(0);
        asm volatile("s_waitcnt lgkmcnt(0)" ::: "memory");
        __builtin_amdgcn_s_barrier();
    }

    #pragma unroll
    for (int j = 0; j < 4; j++) {
        int col = wn * 64 + j * 16 + lr;
        float bv = bias[col];
        float s = 0.f, s2 = 0.f;
        #pragma unroll
        for (int i = 0; i < 4; i++) {
            int row0 = p0 + wm * 64 + i * 16 + lq * 4;
            #pragma unroll
            for (int r = 0; r < 4; r++) {
                float v = acc[i][j][r] + bv;
                y[(size_t)(row0 + r) * COUT + col] = v;
                s += v; s2 += v * v;
            }
        }
        s  += __shfl_down(s, 32);  s  += __shfl_down(s, 16);
        s2 += __shfl_down(s2, 32); s2 += __shfl_down(s2, 16);
        if (lane < 16) {
            atomicAdd(&stats[col], s);
            atomicAdd(&stats[COUT + col], s2);
        }
    }
}

// ---------------- BN(inline fold) + ReLU, emit bf16 into strided (PERZ) layout ---------
// Folds finalize into apply: sc/sh computed per-thread from stats/gamma/beta (broadcast
// loads + rsqrtf, hidden under the memory stream). Zero rows emitted inline.
template<int COUT>
__global__ void apply_kernel(const float* __restrict__ y, const float* __restrict__ stats,
                             const float* __restrict__ gamma, const float* __restrict__ beta,
                             u16* __restrict__ f, int total4) {
    int i = blockIdx.x * blockDim.x + threadIdx.x;          // over BATCH*PERZ*E4
    if (i >= total4) return;
    constexpr int E4 = COUT / 4;
    int p = i / E4, k = i - p * E4;
    int b = p / PERZ, r = p - b * PERZ;
    int c0 = k * 4;
    const float inv_n = 1.f / (float)NTOT;
    float sc[4], sh[4];
    #pragma unroll
    for (int e = 0; e < 4; e++) {
        int c = c0 + e;
        float mu  = stats[c] * inv_n;
        float var = stats[COUT + c] * inv_n - mu * mu;
        sc[e] = gamma[c] * rsqrtf(var + BN_EPS);
        sh[e] = beta[c] - mu * sc[e];
    }
    ushort4 o = make_ushort4(0, 0, 0, 0);
    if (r < PER) {
        float4 v = ((const float4*)y)[(size_t)(b * PER + r) * E4 + k];
        float a;
        a = fmaf(v.x, sc[0], sh[0]); o.x = f2b(a > 0.f ? a : 0.f);
        a = fmaf(v.y, sc[1], sh[1]); o.y = f2b(a > 0.f ? a : 0.f);
        a = fmaf(v.z, sc[2], sh[2]); o.z = f2b(a > 0.f ? a : 0.f);
        a = fmaf(v.w, sc[3], sh[3]); o.w = f2b(a > 0.f ? a : 0.f);
    }
    ((ushort4*)f)[i] = o;
}

// ---------------- legacy dense NCDHW output (from bf16 fbuf) ----------------
__global__ void output_kernel(const u16* __restrict__ f, const int* __restrict__ map,
                              float* __restrict__ out, int total) {
    int i = blockIdx.x * blockDim.x + threadIdx.x;
    if (i >= total) return;
    int voxel = i % VOX;
    int bc    = i / VOX;
    int c = bc & 63;
    int b = bc >> 6;
    int p = map[b * VOX + voxel];
    float v = 0.f;
    if (p >= 0) {
        int r = p - b * PER;
        v = b2f(f[(size_t)(b * PERZ + r) * 64 + c]);
    }
    out[i] = v;
}

// ---------------- fused BN(inline fold)+ReLU+scatter to dense NCDHW --------------------
// One block = (batch b, 64-voxel chunk); requires layer-3 y in its own buffer.
__global__ void output_fused_kernel(const float* __restrict__ y, const float* __restrict__ stats,
                                    const float* __restrict__ gamma, const float* __restrict__ beta,
                                    const int* __restrict__ map, float* __restrict__ out) {
    __shared__ float tile[64][65];                // [voxel][c], +1 pad
    __shared__ int   prow[64];
    const int chunk = blockIdx.x;                 // BATCH * (VOX/64)
    const int b  = chunk / (VOX / 64);
    const int v0 = (chunk % (VOX / 64)) * 64;
    const int t = threadIdx.x;                    // 256
    if (t < 64) prow[t] = map[b * VOX + v0 + t];
    __syncthreads();
    const int c = t & 63;
    const float inv_n = 1.f / (float)NTOT;
    const float mu  = stats[c] * inv_n;
    const float var = stats[64 + c] * inv_n - mu * mu;
    const float sc  = gamma[c] * rsqrtf(var + BN_EPS);
    const float sh  = beta[c] - mu * sc;
    for (int v = t >> 6; v < 64; v += 4) {
        int p = prow[v];
        float val = 0.f;
        if (p >= 0) {
            float a = fmaf(y[(size_t)p * 64 + c], sc, sh);
            val = a > 0.f ? a : 0.f;
        }
        tile[v][c] = val;
    }
    __syncthreads();
    const int vv = t & 63;
    #pragma unroll
    for (int cc = t >> 6; cc < 64; cc += 4)
        out[(size_t)(b * 64 + cc) * VOX + v0 + vv] = tile[vv][cc];
}

extern "C" void kernel_launch(void* const* d_in, const int* in_sizes, int n_in,
                              void* d_out, int out_size, void* d_ws, size_t ws_size,
                              hipStream_t stream) {
    const float* feats = (const float*)d_in[0];
    const int*   idx   = (const int*)  d_in[1];
    const float* W0 = (const float*)d_in[3];
    const float* b0 = (const float*)d_in[4];
    const float* g0 = (const float*)d_in[5];
    const float* e0 = (const float*)d_in[6];
    const float* W1 = (const float*)d_in[7];
    const float* b1 = (const float*)d_in[8];
    const float* g1 = (const float*)d_in[9];
    const float* e1 = (const float*)d_in[10];
    const float* W2 = (const float*)d_in[11];
    const float* b2 = (const float*)d_in[12];
    const float* g2 = (const float*)d_in[13];
    const float* e2 = (const float*)d_in[14];

    const int N = in_sizes[0] / 16;               // 442368

    // ---- workspace layout ----
    char* ws = (char*)d_ws;
    size_t off = 0;
    auto alloc = [&](size_t bytes) { void* p = ws + off; off = (off + bytes + 255) & ~(size_t)255; return p; };
    int*   map   = (int*)  alloc((size_t)BATCH * VOX * 4);
    float* stats = (float*)alloc(3 * 256 * 4);
    u16*   nbr   = (u16*)  alloc((size_t)N * 32 * 2);
    u16*   wt0   = (u16*)  alloc((size_t)64  * 448  * 2);
    u16*   wt1   = (u16*)  alloc((size_t)128 * 1728 * 2);
    u16*   wt2   = (u16*)  alloc((size_t)64  * 3456 * 2);
    u16*   fbuf  = (u16*)  alloc((size_t)BATCH * PERZ * 128 * 2);   // shared by all layers
    float* y = (float*)d_out;                     // fp32 conv out (layers 1/2), aliases d_out

    // layer-3 y gets its own buffer if workspace allows (enables fused output)
    const size_t y3_bytes = (size_t)N * 64 * 4;
    float* y3 = nullptr;
    if (off + y3_bytes <= ws_size) y3 = (float*)alloc(y3_bytes);

    hipMemsetAsync(map,   0xFF, (size_t)BATCH * VOX * 4, stream);
    hipMemsetAsync(stats, 0,    3 * 256 * 4, stream);
    hipMemsetAsync(wt0,   0,    (size_t)64 * 448 * 2, stream);      // zero K-pad
    build_map_kernel<<<(N + 255) / 256, 256, 0, stream>>>(idx, map, N);
    build_nbr_kernel<<<(N + 255) / 256, 256, 0, stream>>>(idx, map, nbr, N);
    transpose_w_kernel<<<(432  * 64  + 255) / 256, 256, 0, stream>>>(W0, wt0, 432,  64,  448);
    transpose_w_kernel<<<(1728 * 128 + 255) / 256, 256, 0, stream>>>(W1, wt1, 1728, 128, 1728);
    transpose_w_kernel<<<(3456 * 64  + 255) / 256, 256, 0, stream>>>(W2, wt2, 3456, 64,  3456);

    // ---- layer 1: 16 -> 64 (BM=256, waves 4x1) ----
    cast_bf16_kernel<<<(BATCH * PERZ * 4 + 255) / 256, 256, 0, stream>>>(feats, fbuf, BATCH * PERZ * 4);
    conv_mfma_kernel<16, 64, 256, 4, 1><<<N / 256, 256, 0, stream>>>(fbuf, nbr, wt0, b0, y, stats + 0);
    apply_kernel<64><<<(BATCH * PERZ * 16 + 255) / 256, 256, 0, stream>>>(y, stats + 0, g0, e0, fbuf, BATCH * PERZ * 16);

    // ---- layer 2: 64 -> 128 (BM=128, waves 2x2) ----
    conv_mfma_kernel<64, 128, 128, 2, 2><<<N / 128, 256, 0, stream>>>(fbuf, nbr, wt1, b1, y, stats + 256);
    apply_kernel<128><<<(BATCH * PERZ * 32 + 255) / 256, 256, 0, stream>>>(y, stats + 256, g1, e1, fbuf, BATCH * PERZ * 32);

    // ---- layer 3: 128 -> 64 (BM=256, waves 4x1) ----
    float* yL3 = y3 ? y3 : y;
    conv_mfma_kernel<128, 64, 256, 4, 1><<<N / 256, 256, 0, stream>>>(fbuf, nbr, wt2, b2, yL3, stats + 512);

    if (y3) {
        // fused BN+ReLU+scatter straight from y3 (no fbuf round-trip)
        output_fused_kernel<<<BATCH * (VOX / 64), 256, 0, stream>>>(y3, stats + 512, g2, e2, map, (float*)d_out);
    } else {
        apply_kernel<64><<<(BATCH * PERZ * 16 + 255) / 256, 256, 0, stream>>>(y, stats + 512, g2, e2, fbuf, BATCH * PERZ * 16);
        output_kernel<<<(out_size + 255) / 256, 256, 0, stream>>>(fbuf, map, (float*)d_out, out_size);
    }
}